// Round 12
// baseline (107.575 us; speedup 1.0000x reference)
//
#include <hip/hip_runtime.h>
#include <hip/hip_bf16.h>

// Problem constants (B=2, H=W=112, C=256, NHEAD=8, STRIP=7)
#define M_ROWS 25088
#define CDIM   256
#define QKVD   768
#define LWIN   784
#define NWINH  256   // 32 windows * 8 heads

typedef __attribute__((ext_vector_type(8))) short short8v;
typedef __attribute__((ext_vector_type(4))) float floatx4;

// scale * log2(e) = (1/sqrt(32)) * 1.4426950408889634
#define CEQ 0.2550660106245232f

static __device__ __forceinline__ unsigned short f2bf(float f) {
    unsigned int x = __float_as_uint(f);
    x += 0x7fffu + ((x >> 16) & 1u);
    return (unsigned short)(x >> 16);
}
static __device__ __forceinline__ unsigned int cvt_pk_bf16(float a, float b) {
    unsigned int r;
    asm("v_cvt_pk_bf16_f32 %0, %1, %2" : "=v"(r) : "v"(a), "v"(b));
    return r;  // lo16 = bf16(a), hi16 = bf16(b)
}
static __device__ __forceinline__ void gld_lds16(const unsigned short* g,
                                                 unsigned short* l) {
    __builtin_amdgcn_global_load_lds(
        (const __attribute__((address_space(1))) unsigned int*)g,
        (__attribute__((address_space(3))) unsigned int*)l, 16, 0, 0);
}

// ---------------------------------------------------------------------------
// Kernel 1/3: C(M,N) = A(M,256) @ B(N,256)^T [+ bias], bf16 MFMA.
// 128x128 tile, BK=64, 256 threads = 4 waves (2x2), 64x64 per wave.
// A_FP32/B_FP32: operand is fp32 in global; staged with in-register
// v_cvt_pk_bf16_f32 (same instruction/rounding as the old f2bf pass ->
// bitwise-identical LDS tiles) — eliminates the standalone conversion
// kernel and its 78 MB of HBM traffic. bf16 operands keep global_load_lds.
// SCALEQ: cols 0..255 (the Q block of qkv) scaled by CEQ in the epilogue.
// ---------------------------------------------------------------------------
template <typename OUT_T, bool BIAS, bool SCALEQ, bool A_FP32, bool B_FP32>
__global__ __launch_bounds__(256, 2) void k_gemm_mfma(
    const void* __restrict__ Av,            // (M, 256) bf16 or fp32
    const void* __restrict__ Bv,            // (N, 256) bf16 or fp32
    const float* __restrict__ bias,         // (N) or nullptr
    OUT_T* __restrict__ Y, int N)           // (M, N)
{
    __shared__ __attribute__((aligned(16))) unsigned short As[128 * 64];
    __shared__ __attribute__((aligned(16))) unsigned short Bs[128 * 64];
    const int t = threadIdx.x;
    const int lane = t & 63, wv = t >> 6;
    const int lq = lane & 15, g = lane >> 4;
    const int wm = wv >> 1, wn = wv & 1;
    const int R0 = blockIdx.y * 128, C0 = blockIdx.x * 128;
    const int lrow = t >> 3, lch = (t & 7) * 8;   // gld_lds mapping
    const int srow = t >> 3, scol = (t & 7) * 8;  // reg-stage mapping

    floatx4 acc[4][4];
#pragma unroll
    for (int i = 0; i < 4; ++i)
#pragma unroll
        for (int j = 0; j < 4; ++j) acc[i][j] = (floatx4){0.f, 0.f, 0.f, 0.f};

    for (int kc = 0; kc < 256; kc += 64) {
        if constexpr (A_FP32) {
            const float* A = (const float*)Av;
#pragma unroll
            for (int i = 0; i < 4; ++i) {
                const float* src = A + (size_t)(R0 + i * 32 + srow) * 256 + kc + scol;
                float4 a0 = *(const float4*)src;
                float4 a1 = *(const float4*)(src + 4);
                uint4 o;
                o.x = cvt_pk_bf16(a0.x, a0.y);
                o.y = cvt_pk_bf16(a0.z, a0.w);
                o.z = cvt_pk_bf16(a1.x, a1.y);
                o.w = cvt_pk_bf16(a1.z, a1.w);
                *(uint4*)(As + (i * 32 + srow) * 64 + scol) = o;
            }
        } else {
            const unsigned short* A = (const unsigned short*)Av;
#pragma unroll
            for (int i = 0; i < 4; ++i)
                gld_lds16(A + (size_t)(R0 + i * 32 + lrow) * 256 + kc + lch,
                          As + (i * 32 + wv * 8) * 64);
        }
        if constexpr (B_FP32) {
            const float* B = (const float*)Bv;
#pragma unroll
            for (int i = 0; i < 4; ++i) {
                const float* src = B + (size_t)(C0 + i * 32 + srow) * 256 + kc + scol;
                float4 b0 = *(const float4*)src;
                float4 b1 = *(const float4*)(src + 4);
                uint4 o;
                o.x = cvt_pk_bf16(b0.x, b0.y);
                o.y = cvt_pk_bf16(b0.z, b0.w);
                o.z = cvt_pk_bf16(b1.x, b1.y);
                o.w = cvt_pk_bf16(b1.z, b1.w);
                *(uint4*)(Bs + (i * 32 + srow) * 64 + scol) = o;
            }
        } else {
            const unsigned short* B = (const unsigned short*)Bv;
#pragma unroll
            for (int i = 0; i < 4; ++i)
                gld_lds16(B + (size_t)(C0 + i * 32 + lrow) * 256 + kc + lch,
                          Bs + (i * 32 + wv * 8) * 64);
        }
        __syncthreads();
#pragma unroll
        for (int kk = 0; kk < 64; kk += 32) {
            short8v af[4], bf[4];
#pragma unroll
            for (int mi = 0; mi < 4; ++mi)
                af[mi] = *(const short8v*)(As + (wm * 64 + mi * 16 + lq) * 64 +
                                           kk + g * 8);
#pragma unroll
            for (int ni = 0; ni < 4; ++ni)
                bf[ni] = *(const short8v*)(Bs + (wn * 64 + ni * 16 + lq) * 64 +
                                           kk + g * 8);
#pragma unroll
            for (int mi = 0; mi < 4; ++mi)
#pragma unroll
                for (int ni = 0; ni < 4; ++ni)
                    acc[mi][ni] = __builtin_amdgcn_mfma_f32_16x16x32_bf16(
                        af[mi], bf[ni], acc[mi][ni], 0, 0, 0);
        }
        __syncthreads();
    }

#pragma unroll
    for (int mi = 0; mi < 4; ++mi) {
        const size_t rb = (size_t)R0 + wm * 64 + mi * 16 + g * 4;
#pragma unroll
        for (int ni = 0; ni < 4; ++ni) {
            const int col = C0 + wn * 64 + ni * 16 + lq;
            float bv = 0.f;
            if constexpr (BIAS) bv = bias[col];
#pragma unroll
            for (int r = 0; r < 4; ++r) {
                float val = acc[mi][ni][r];
                if constexpr (SCALEQ) { if (col < 256) val *= CEQ; }
                val += bv;
                if constexpr (sizeof(OUT_T) == 2)
                    Y[(rb + r) * N + col] = (OUT_T)f2bf(val);
                else
                    Y[(rb + r) * N + col] = (OUT_T)val;
            }
        }
    }
}

// ---------------------------------------------------------------------------
// Kernel 2: MFMA attention — R5/R11 kernel (verified 45.2us) with T5
// setprio. P kept in registers via permuted k-order (pos 8g+j <-> token
// (j>=4?16:0)+4g+(j&3)); V staged with matching permutation. K: [784][36]
// shorts. V: [32][404] u32 token-pair words. 16 waves, 1 block/CU;
// wave 0: 4 q-tiles, waves 1..15: 3.
// ---------------------------------------------------------------------------
#define KPITCH 36
#define VPITCH 404                         // u32 words per d-row
#define KS_SZ  (LWIN * KPITCH)             // 28224 shorts = 56448 B
#define ATTN_LDS (KS_SZ * 2 + 32 * VPITCH * 4)   // 108160 bytes

__global__ __launch_bounds__(1024, 1) void k_attn_mfma(
    const unsigned short* __restrict__ qkv,   // (25088, 768) bf16
    unsigned short* __restrict__ ao)          // (25088, 256) bf16
{
    extern __shared__ unsigned short sm[];
    unsigned short* Ks = sm;                           // [784][36]
    unsigned int*   Vt = (unsigned int*)(sm + KS_SZ);  // [32][404]
    const int t = threadIdx.x;
    const int lane = t & 63, wave = t >> 6;
    const int lq = lane & 15, g = lane >> 4;
    const int h = blockIdx.x & 7, w = blockIdx.x >> 3;
    const size_t rowbase = (size_t)w * LWIN;
    const unsigned short* base = qkv + rowbase * QKVD;

    // ---- stage K: [784][36] ----
    for (int idx = t; idx < LWIN * 4; idx += 1024) {
        const int row = idx >> 2, c = idx & 3;
        uint4 kv = *(const uint4*)(base + (size_t)row * QKVD + 256 + h * 32 + c * 8);
        *(uint4*)(Ks + row * KPITCH + c * 8) = kv;
    }
    // ---- stage V: permuted-position packed token-pairs ----
    {
        const int c = t >> 8;          // d-octet 0..3
        const int p0 = t & 255;
        for (int tp = p0; tp < 392; tp += 256) {
            const int u = tp >> 4, tpp = tp & 15;
            const int a = tpp >> 3, gg = (tpp >> 1) & 3, rp = tpp & 1;
            const int wrd = u * 16 + gg * 4 + a * 2 + rp;
            union { uint4 u4; unsigned short s[8]; } x0, x1;
            x0.u4 = *(const uint4*)(base + (size_t)(2 * tp) * QKVD + 512 + h * 32 + c * 8);
            x1.u4 = *(const uint4*)(base + (size_t)(2 * tp + 1) * QKVD + 512 + h * 32 + c * 8);
#pragma unroll
            for (int j = 0; j < 8; ++j)
                Vt[(c * 8 + j) * VPITCH + wrd] =
                    (unsigned int)x0.s[j] | ((unsigned int)x1.s[j] << 16);
        }
    }
    // zero block-24's a=1 words (positions for the missing s=49 tile)
    for (int idx = t; idx < 32 * 8; idx += 1024) {
        const int d = idx >> 3, q = idx & 7;
        Vt[d * VPITCH + 384 + (q >> 1) * 4 + 2 + (q & 1)] = 0;
    }
    __syncthreads();

    // ---- per-wave q-tiles: wave 0 -> {0..3}, wave w -> {3w+1..3w+3} ----
    const int ntile = (wave == 0) ? 4 : 3;
    const int tbase = (wave == 0) ? 0 : (3 * wave + 1);

    short8v qf[4];
#pragma unroll
    for (int n = 0; n < 4; ++n)
        if (n < ntile)
            qf[n] = *(const short8v*)(base +
                    (size_t)((tbase + n) * 16 + lq) * QKVD + h * 32 + g * 8);

    floatx4 oa[4][2];
#pragma unroll
    for (int n = 0; n < 4; ++n) {
        oa[n][0] = (floatx4){0.f, 0.f, 0.f, 0.f};
        oa[n][1] = (floatx4){0.f, 0.f, 0.f, 0.f};
    }
    float lsum[4] = {0.f, 0.f, 0.f, 0.f};

    for (int u = 0; u < 25; ++u) {
        unsigned int pw[4][4];
        __builtin_amdgcn_s_setprio(1);
        {   // s = 2u
            short8v kf = *(const short8v*)(Ks + (size_t)(2 * u * 16 + lq) * KPITCH + g * 8);
#pragma unroll
            for (int n = 0; n < 4; ++n) if (n < ntile) {
                floatx4 st = __builtin_amdgcn_mfma_f32_16x16x32_bf16(
                    kf, qf[n], (floatx4){0.f, 0.f, 0.f, 0.f}, 0, 0, 0);
                float p0 = __builtin_amdgcn_exp2f(st[0]);
                float p1 = __builtin_amdgcn_exp2f(st[1]);
                float p2 = __builtin_amdgcn_exp2f(st[2]);
                float p3 = __builtin_amdgcn_exp2f(st[3]);
                lsum[n] += (p0 + p1) + (p2 + p3);
                pw[n][0] = cvt_pk_bf16(p0, p1);
                pw[n][1] = cvt_pk_bf16(p2, p3);
            }
        }
        if (u < 24) {   // s = 2u+1
            short8v kf = *(const short8v*)(Ks + (size_t)((2 * u + 1) * 16 + lq) * KPITCH + g * 8);
#pragma unroll
            for (int n = 0; n < 4; ++n) if (n < ntile) {
                floatx4 st = __builtin_amdgcn_mfma_f32_16x16x32_bf16(
                    kf, qf[n], (floatx4){0.f, 0.f, 0.f, 0.f}, 0, 0, 0);
                float p0 = __builtin_amdgcn_exp2f(st[0]);
                float p1 = __builtin_amdgcn_exp2f(st[1]);
                float p2 = __builtin_amdgcn_exp2f(st[2]);
                float p3 = __builtin_amdgcn_exp2f(st[3]);
                lsum[n] += (p0 + p1) + (p2 + p3);
                pw[n][2] = cvt_pk_bf16(p0, p1);
                pw[n][3] = cvt_pk_bf16(p2, p3);
            }
        } else {
#pragma unroll
            for (int n = 0; n < 4; ++n) if (n < ntile) {
                pw[n][2] = 0u; pw[n][3] = 0u;
            }
        }
        // ---- PV: A-frag = own pw words (permuted k-order), B = V from LDS ----
        const unsigned short* vrow0 = (const unsigned short*)Vt;
        short8v v0 = *(const short8v*)(vrow0 + (size_t)lq * (VPITCH * 2) + u * 32 + g * 8);
        short8v v1 = *(const short8v*)(vrow0 + (size_t)(lq + 16) * (VPITCH * 2) + u * 32 + g * 8);
#pragma unroll
        for (int n = 0; n < 4; ++n) if (n < ntile) {
            union { unsigned int wd[4]; short8v v; } pu;
            pu.wd[0] = pw[n][0]; pu.wd[1] = pw[n][1];
            pu.wd[2] = pw[n][2]; pu.wd[3] = pw[n][3];
            oa[n][0] = __builtin_amdgcn_mfma_f32_16x16x32_bf16(pu.v, v0, oa[n][0], 0, 0, 0);
            oa[n][1] = __builtin_amdgcn_mfma_f32_16x16x32_bf16(pu.v, v1, oa[n][1], 0, 0, 0);
        }
        __builtin_amdgcn_s_setprio(0);
    }

    // ---- normalize + store ----
#pragma unroll
    for (int n = 0; n < 4; ++n) if (n < ntile) {
        float l = lsum[n];
        l += __shfl_xor(l, 16);
        l += __shfl_xor(l, 32);
        float inv = 1.f / l;
        const size_t orow0 = rowbase + (size_t)(tbase + n) * 16;
#pragma unroll
        for (int r = 0; r < 4; ++r) {
            float ir = __shfl(inv, (lane & 48) | (g * 4 + r));
            size_t ob = (orow0 + g * 4 + r) * CDIM + h * 32;
            ao[ob + lq]      = f2bf(oa[n][0][r] * ir);
            ao[ob + 16 + lq] = f2bf(oa[n][1][r] * ir);
        }
    }
}

extern "C" void kernel_launch(void* const* d_in, const int* in_sizes, int n_in,
                              void* d_out, int out_size, void* d_ws, size_t ws_size,
                              hipStream_t stream) {
    const float* x      = (const float*)d_in[0];
    const float* qkv_w  = (const float*)d_in[1];
    const float* proj_w = (const float*)d_in[2];
    const float* proj_b = (const float*)d_in[3];
    float* out = (float*)d_out;

    // ws layout: qkvb (25088x768 bf16) | aob (25088x256 bf16)
    unsigned short* qkvb = (unsigned short*)d_ws;
    unsigned short* aob  = qkvb + (size_t)M_ROWS * QKVD;

    hipFuncSetAttribute((const void*)k_attn_mfma,
                        hipFuncAttributeMaxDynamicSharedMemorySize, ATTN_LDS);

    // GEMM1: qkv = x @ qkv_w^T, fp32 inputs converted in-staging.
    k_gemm_mfma<unsigned short, false, true, true, true>
        <<<dim3(QKVD / 128, M_ROWS / 128), 256, 0, stream>>>(
            x, qkv_w, nullptr, qkvb, QKVD);

    k_attn_mfma<<<dim3(NWINH), 1024, ATTN_LDS, stream>>>(qkvb, aob);

    // GEMM2: out = ao @ proj_w^T + b; bf16 A via gld_lds, fp32 B in-staging.
    k_gemm_mfma<float, true, false, false, true>
        <<<dim3(CDIM / 128, M_ROWS / 128), 256, 0, stream>>>(
            aob, proj_w, proj_b, out, CDIM);
}

// Round 13
// 84.620 us; speedup vs baseline: 1.2713x; 1.2713x over previous
//
#include <hip/hip_runtime.h>
#include <hip/hip_bf16.h>

// Problem constants (B=2, H=W=112, C=256, NHEAD=8, STRIP=7)
#define M_ROWS 25088
#define CDIM   256
#define QKVD   768
#define LWIN   784
#define NWINH  256   // 32 windows * 8 heads

typedef __attribute__((ext_vector_type(8))) short short8v;
typedef __attribute__((ext_vector_type(4))) float floatx4;

// scale * log2(e) = (1/sqrt(32)) * 1.4426950408889634
#define CEQ 0.2550660106245232f

static __device__ __forceinline__ unsigned short f2bf(float f) {
    unsigned int x = __float_as_uint(f);
    x += 0x7fffu + ((x >> 16) & 1u);
    return (unsigned short)(x >> 16);
}
static __device__ __forceinline__ unsigned int cvt_pk_bf16(float a, float b) {
    unsigned int r;
    asm("v_cvt_pk_bf16_f32 %0, %1, %2" : "=v"(r) : "v"(a), "v"(b));
    return r;  // lo16 = bf16(a), hi16 = bf16(b)
}
static __device__ __forceinline__ void gld_lds16(const unsigned short* g,
                                                 unsigned short* l) {
    __builtin_amdgcn_global_load_lds(
        (const __attribute__((address_space(1))) unsigned int*)g,
        (__attribute__((address_space(3))) unsigned int*)l, 16, 0, 0);
}

// ---------------------------------------------------------------------------
// Kernel 0: fp32 -> bf16 pack, all three tensors in ONE launch. [R11 verbatim]
// ---------------------------------------------------------------------------
#define N8_TOTAL ((M_ROWS * CDIM + QKVD * CDIM + CDIM * CDIM) / 8)

__global__ __launch_bounds__(256) void k_f2bf3(
    const float* __restrict__ s0,   // x       (M_ROWS*CDIM)
    const float* __restrict__ s1,   // qkv_w   (QKVD*CDIM)
    const float* __restrict__ s2,   // proj_w  (CDIM*CDIM)
    unsigned short* __restrict__ d0,
    unsigned short* __restrict__ d1,
    unsigned short* __restrict__ d2)
{
    const int n80 = (M_ROWS * CDIM) / 8;
    const int n81 = (QKVD * CDIM) / 8;
    for (int i = blockIdx.x * 256 + threadIdx.x; i < N8_TOTAL;
         i += gridDim.x * 256) {
        const float4* s4;
        uint4* d4;
        int j = i;
        if (j < n80)            { s4 = (const float4*)s0; d4 = (uint4*)d0; }
        else if ((j -= n80) < n81) { s4 = (const float4*)s1; d4 = (uint4*)d1; }
        else                    { j -= n81; s4 = (const float4*)s2; d4 = (uint4*)d2; }
        float4 a = s4[2 * j], b = s4[2 * j + 1];
        uint4 o;
        o.x = cvt_pk_bf16(a.x, a.y);
        o.y = cvt_pk_bf16(a.z, a.w);
        o.z = cvt_pk_bf16(b.x, b.y);
        o.w = cvt_pk_bf16(b.z, b.w);
        d4[j] = o;
    }
}

// ---------------------------------------------------------------------------
// Kernel 1/3: C(M,N) = A(M,256) @ B(N,256)^T [+ bias], bf16 MFMA.
// [R11 verbatim — gld_lds staging for BOTH operands; R12's fused fp32
// staging regressed 3.4x (sync loads serialize staging, 2x HBM fetch).]
// ---------------------------------------------------------------------------
template <typename OUT_T, bool BIAS, bool SCALEQ>
__global__ __launch_bounds__(256, 2) void k_gemm_mfma(
    const unsigned short* __restrict__ A,   // (M, 256) bf16
    const unsigned short* __restrict__ B,   // (N, 256) bf16
    const float* __restrict__ bias,         // (N) or nullptr
    OUT_T* __restrict__ Y, int N)           // (M, N)
{
    __shared__ __attribute__((aligned(16))) unsigned short As[128 * 64];
    __shared__ __attribute__((aligned(16))) unsigned short Bs[128 * 64];
    const int t = threadIdx.x;
    const int lane = t & 63, wv = t >> 6;
    const int lq = lane & 15, g = lane >> 4;
    const int wm = wv >> 1, wn = wv & 1;
    const int R0 = blockIdx.y * 128, C0 = blockIdx.x * 128;
    const int lrow = t >> 3, lch = (t & 7) * 8;

    floatx4 acc[4][4];
#pragma unroll
    for (int i = 0; i < 4; ++i)
#pragma unroll
        for (int j = 0; j < 4; ++j) acc[i][j] = (floatx4){0.f, 0.f, 0.f, 0.f};

    for (int kc = 0; kc < 256; kc += 64) {
#pragma unroll
        for (int i = 0; i < 4; ++i) {
            gld_lds16(A + (size_t)(R0 + i * 32 + lrow) * 256 + kc + lch,
                      As + (i * 32 + wv * 8) * 64);
            gld_lds16(B + (size_t)(C0 + i * 32 + lrow) * 256 + kc + lch,
                      Bs + (i * 32 + wv * 8) * 64);
        }
        __syncthreads();
#pragma unroll
        for (int kk = 0; kk < 64; kk += 32) {
            short8v af[4], bf[4];
#pragma unroll
            for (int mi = 0; mi < 4; ++mi)
                af[mi] = *(const short8v*)(As + (wm * 64 + mi * 16 + lq) * 64 +
                                           kk + g * 8);
#pragma unroll
            for (int ni = 0; ni < 4; ++ni)
                bf[ni] = *(const short8v*)(Bs + (wn * 64 + ni * 16 + lq) * 64 +
                                           kk + g * 8);
#pragma unroll
            for (int mi = 0; mi < 4; ++mi)
#pragma unroll
                for (int ni = 0; ni < 4; ++ni)
                    acc[mi][ni] = __builtin_amdgcn_mfma_f32_16x16x32_bf16(
                        af[mi], bf[ni], acc[mi][ni], 0, 0, 0);
        }
        __syncthreads();
    }

#pragma unroll
    for (int mi = 0; mi < 4; ++mi) {
        const size_t rb = (size_t)R0 + wm * 64 + mi * 16 + g * 4;
#pragma unroll
        for (int ni = 0; ni < 4; ++ni) {
            const int col = C0 + wn * 64 + ni * 16 + lq;
            float bv = 0.f;
            if constexpr (BIAS) bv = bias[col];
#pragma unroll
            for (int r = 0; r < 4; ++r) {
                float val = acc[mi][ni][r];
                if constexpr (SCALEQ) { if (col < 256) val *= CEQ; }
                val += bv;
                if constexpr (sizeof(OUT_T) == 2)
                    Y[(rb + r) * N + col] = (OUT_T)f2bf(val);
                else
                    Y[(rb + r) * N + col] = (OUT_T)val;
            }
        }
    }
}

// ---------------------------------------------------------------------------
// Kernel 2: MFMA attention, register-P — now LOAD-BALANCED: every wave owns
// tiles {w, w+16, w+32} (uniform 3) and q-tile 48 is split across all 16
// waves by u-range (waves 0-8: 2 u's, 9-15: 1), reusing the per-u kf/v
// loads. Partials reduced via a dedicated LDS buffer by wave 0 at the end.
// K: [784][36] shorts. V: [32][404] u32 token-pair words (permuted k-order:
// pos 8g+j <-> token (j>=4?16:0)+4g+(j&3)). 1 block/CU, 16 waves.
// ---------------------------------------------------------------------------
#define KPITCH 36
#define VPITCH 404                         // u32 words per d-row
#define KS_SZ  (LWIN * KPITCH)             // 28224 shorts = 56448 B
#define VT_SH  (32 * VPITCH * 2)           // 25856 shorts = 51712 B
#define PART_OFF (KS_SZ + VT_SH)           // 54080 shorts
#define PART_BYTES (16 * 64 * 12 * 4)      // 49152 B
#define ATTN_LDS (PART_OFF * 2 + PART_BYTES)   // 157312 bytes

__global__ __launch_bounds__(1024, 1) void k_attn_mfma(
    const unsigned short* __restrict__ qkv,   // (25088, 768) bf16
    unsigned short* __restrict__ ao)          // (25088, 256) bf16
{
    extern __shared__ unsigned short sm[];
    unsigned short* Ks = sm;                           // [784][36]
    unsigned int*   Vt = (unsigned int*)(sm + KS_SZ);  // [32][404]
    float*          pb = (float*)(sm + PART_OFF);      // [16][64][12]
    const int t = threadIdx.x;
    const int lane = t & 63, wave = t >> 6;
    const int lq = lane & 15, g = lane >> 4;
    const int h = blockIdx.x & 7, w = blockIdx.x >> 3;
    const size_t rowbase = (size_t)w * LWIN;
    const unsigned short* base = qkv + rowbase * QKVD;

    // ---- stage K: [784][36] ----
    for (int idx = t; idx < LWIN * 4; idx += 1024) {
        const int row = idx >> 2, c = idx & 3;
        uint4 kv = *(const uint4*)(base + (size_t)row * QKVD + 256 + h * 32 + c * 8);
        *(uint4*)(Ks + row * KPITCH + c * 8) = kv;
    }
    // ---- stage V: permuted-position packed token-pairs ----
    {
        const int c = t >> 8;          // d-octet 0..3
        const int p0 = t & 255;
        for (int tp = p0; tp < 392; tp += 256) {
            const int u = tp >> 4, tpp = tp & 15;
            const int a = tpp >> 3, gg = (tpp >> 1) & 3, rp = tpp & 1;
            const int wrd = u * 16 + gg * 4 + a * 2 + rp;
            union { uint4 u4; unsigned short s[8]; } x0, x1;
            x0.u4 = *(const uint4*)(base + (size_t)(2 * tp) * QKVD + 512 + h * 32 + c * 8);
            x1.u4 = *(const uint4*)(base + (size_t)(2 * tp + 1) * QKVD + 512 + h * 32 + c * 8);
#pragma unroll
            for (int j = 0; j < 8; ++j)
                Vt[(c * 8 + j) * VPITCH + wrd] =
                    (unsigned int)x0.s[j] | ((unsigned int)x1.s[j] << 16);
        }
    }
    // zero block-24's a=1 words (positions for the missing s=49 tile)
    for (int idx = t; idx < 32 * 8; idx += 1024) {
        const int d = idx >> 3, q = idx & 7;
        Vt[d * VPITCH + 384 + (q >> 1) * 4 + 2 + (q & 1)] = 0;
    }
    __syncthreads();

    // ---- per-wave q-tiles: uniform {w, w+16, w+32}; tile 48 split by u ----
    const int myu0 = (wave < 9) ? 2 * wave : wave + 9;
    const int myu1 = (wave < 9) ? 2 * wave + 2 : wave + 10;

    short8v qf[4];
#pragma unroll
    for (int n = 0; n < 3; ++n)
        qf[n] = *(const short8v*)(base +
                (size_t)((wave + n * 16) * 16 + lq) * QKVD + h * 32 + g * 8);
    qf[3] = *(const short8v*)(base +
            (size_t)(48 * 16 + lq) * QKVD + h * 32 + g * 8);

    floatx4 oa[4][2];
#pragma unroll
    for (int n = 0; n < 4; ++n) {
        oa[n][0] = (floatx4){0.f, 0.f, 0.f, 0.f};
        oa[n][1] = (floatx4){0.f, 0.f, 0.f, 0.f};
    }
    float lsum[4] = {0.f, 0.f, 0.f, 0.f};

    for (int u = 0; u < 25; ++u) {
        const bool do48 = (u >= myu0) && (u < myu1);
        unsigned int pw[4][4];
        __builtin_amdgcn_s_setprio(1);
        {   // s = 2u
            short8v kf = *(const short8v*)(Ks + (size_t)(2 * u * 16 + lq) * KPITCH + g * 8);
#pragma unroll
            for (int n = 0; n < 4; ++n) if (n < 3 || do48) {
                floatx4 st = __builtin_amdgcn_mfma_f32_16x16x32_bf16(
                    kf, qf[n], (floatx4){0.f, 0.f, 0.f, 0.f}, 0, 0, 0);
                float p0 = __builtin_amdgcn_exp2f(st[0]);
                float p1 = __builtin_amdgcn_exp2f(st[1]);
                float p2 = __builtin_amdgcn_exp2f(st[2]);
                float p3 = __builtin_amdgcn_exp2f(st[3]);
                lsum[n] += (p0 + p1) + (p2 + p3);
                pw[n][0] = cvt_pk_bf16(p0, p1);
                pw[n][1] = cvt_pk_bf16(p2, p3);
            }
        }
        if (u < 24) {   // s = 2u+1
            short8v kf = *(const short8v*)(Ks + (size_t)((2 * u + 1) * 16 + lq) * KPITCH + g * 8);
#pragma unroll
            for (int n = 0; n < 4; ++n) if (n < 3 || do48) {
                floatx4 st = __builtin_amdgcn_mfma_f32_16x16x32_bf16(
                    kf, qf[n], (floatx4){0.f, 0.f, 0.f, 0.f}, 0, 0, 0);
                float p0 = __builtin_amdgcn_exp2f(st[0]);
                float p1 = __builtin_amdgcn_exp2f(st[1]);
                float p2 = __builtin_amdgcn_exp2f(st[2]);
                float p3 = __builtin_amdgcn_exp2f(st[3]);
                lsum[n] += (p0 + p1) + (p2 + p3);
                pw[n][2] = cvt_pk_bf16(p0, p1);
                pw[n][3] = cvt_pk_bf16(p2, p3);
            }
        } else {
#pragma unroll
            for (int n = 0; n < 4; ++n) if (n < 3 || do48) {
                pw[n][2] = 0u; pw[n][3] = 0u;
            }
        }
        // ---- PV: A-frag = own pw words (permuted k-order), B = V from LDS ----
        const unsigned short* vrow0 = (const unsigned short*)Vt;
        short8v v0 = *(const short8v*)(vrow0 + (size_t)lq * (VPITCH * 2) + u * 32 + g * 8);
        short8v v1 = *(const short8v*)(vrow0 + (size_t)(lq + 16) * (VPITCH * 2) + u * 32 + g * 8);
#pragma unroll
        for (int n = 0; n < 4; ++n) if (n < 3 || do48) {
            union { unsigned int wd[4]; short8v v; } pu;
            pu.wd[0] = pw[n][0]; pu.wd[1] = pw[n][1];
            pu.wd[2] = pw[n][2]; pu.wd[3] = pw[n][3];
            oa[n][0] = __builtin_amdgcn_mfma_f32_16x16x32_bf16(pu.v, v0, oa[n][0], 0, 0, 0);
            oa[n][1] = __builtin_amdgcn_mfma_f32_16x16x32_bf16(pu.v, v1, oa[n][1], 0, 0, 0);
        }
        __builtin_amdgcn_s_setprio(0);
    }

    // ---- normalize + store main tiles {wave, wave+16, wave+32} ----
#pragma unroll
    for (int n = 0; n < 3; ++n) {
        float l = lsum[n];
        l += __shfl_xor(l, 16);
        l += __shfl_xor(l, 32);
        float inv = 1.f / l;
        const size_t orow0 = rowbase + (size_t)(wave + n * 16) * 16;
#pragma unroll
        for (int r = 0; r < 4; ++r) {
            float ir = __shfl(inv, (lane & 48) | (g * 4 + r));
            size_t ob = (orow0 + g * 4 + r) * CDIM + h * 32;
            ao[ob + lq]      = f2bf(oa[n][0][r] * ir);
            ao[ob + 16 + lq] = f2bf(oa[n][1][r] * ir);
        }
    }

    // ---- tile 48: write partials, reduce on wave 0, store rows 768..783 ----
    {
        float* mypb = pb + (wave * 64 + lane) * 12;
#pragma unroll
        for (int r = 0; r < 4; ++r) {
            mypb[r]     = oa[3][0][r];
            mypb[4 + r] = oa[3][1][r];
        }
        mypb[8] = lsum[3];
    }
    __syncthreads();
    if (wave == 0) {
        floatx4 s0 = {0.f, 0.f, 0.f, 0.f}, s1 = {0.f, 0.f, 0.f, 0.f};
        float sl = 0.f;
        for (int v2 = 0; v2 < 16; ++v2) {
            const float* q = pb + (v2 * 64 + lane) * 12;
            floatx4 a0 = *(const floatx4*)q;
            floatx4 a1 = *(const floatx4*)(q + 4);
            s0 += a0; s1 += a1;
            sl += q[8];
        }
        sl += __shfl_xor(sl, 16);
        sl += __shfl_xor(sl, 32);
        float inv = 1.f / sl;
        const size_t orow0 = rowbase + 768;
#pragma unroll
        for (int r = 0; r < 4; ++r) {
            float ir = __shfl(inv, (lane & 48) | (g * 4 + r));
            size_t ob = (orow0 + g * 4 + r) * CDIM + h * 32;
            ao[ob + lq]      = f2bf(s0[r] * ir);
            ao[ob + 16 + lq] = f2bf(s1[r] * ir);
        }
    }
}

extern "C" void kernel_launch(void* const* d_in, const int* in_sizes, int n_in,
                              void* d_out, int out_size, void* d_ws, size_t ws_size,
                              hipStream_t stream) {
    const float* x      = (const float*)d_in[0];
    const float* qkv_w  = (const float*)d_in[1];
    const float* proj_w = (const float*)d_in[2];
    const float* proj_b = (const float*)d_in[3];
    float* out = (float*)d_out;

    unsigned short* qkvb = (unsigned short*)d_ws;
    unsigned short* xb   = qkvb + (size_t)M_ROWS * QKVD;
    unsigned short* aob  = xb;  // alias: xb dead once GEMM1 completes
    unsigned short* wqb  = xb + (size_t)M_ROWS * CDIM;
    unsigned short* wpb  = wqb + (size_t)QKVD * CDIM;

    hipFuncSetAttribute((const void*)k_attn_mfma,
                        hipFuncAttributeMaxDynamicSharedMemorySize, ATTN_LDS);

    k_f2bf3<<<2048, 256, 0, stream>>>(x, qkv_w, proj_w, xb, wqb, wpb);

    k_gemm_mfma<unsigned short, false, true>
        <<<dim3(QKVD / 128, M_ROWS / 128), 256, 0, stream>>>(
            xb, wqb, nullptr, qkvb, QKVD);

    k_attn_mfma<<<dim3(NWINH), 1024, ATTN_LDS, stream>>>(qkvb, aob);

    k_gemm_mfma<float, true, false>
        <<<dim3(CDIM / 128, M_ROWS / 128), 256, 0, stream>>>(
            aob, wpb, proj_b, out, CDIM);
}